// Round 9
// baseline (211.681 us; speedup 1.0000x reference)
//
#include <hip/hip_runtime.h>

#define I_DIM 28
#define H_DIM 64
#define T_DIM 128
#define B_DIM 4096
#define OUT_DIM 10
#define MB 4          // batch rows per block
#define NTHREADS 256  // 4 waves; wave wv owns units 16wv..16wv+15, all 4 gates
#define LOG2E 1.44269504088896340736f

typedef __attribute__((ext_vector_type(8))) short bf16x8;
typedef __attribute__((ext_vector_type(4))) float f32x4;
typedef __attribute__((ext_vector_type(4))) unsigned u32x4;

__device__ __forceinline__ float bfbits2f(unsigned b16) {
    return __builtin_bit_cast(float, b16 << 16);
}
__device__ __forceinline__ unsigned rne_u(float f) {
    unsigned u = __builtin_bit_cast(unsigned, f);
    return u + 0x7FFFu + ((u >> 16) & 1u);
}
// pack two floats -> (bf16(b)<<16)|bf16(a)
__device__ __forceinline__ unsigned pack_pair(float a, float b) {
    return __builtin_amdgcn_perm(rne_u(b), rne_u(a), 0x07060302u);
}
__device__ __forceinline__ unsigned f2bf_rne(float f) { return rne_u(f) >> 16; }

// 8 floats -> single rne-bf16 frag (4 dwords)
__device__ __forceinline__ bf16x8 pack_frag(const float* v) {
    u32x4 w;
    #pragma unroll
    for (int i = 0; i < 4; ++i) w[i] = pack_pair(v[2*i], v[2*i+1]);
    return __builtin_bit_cast(bf16x8, w);
}

__device__ __forceinline__ float fast_rcp(float v) { return __builtin_amdgcn_rcpf(v); }
__device__ __forceinline__ float exp2_f(float v)  { return __builtin_amdgcn_exp2f(v); }
__device__ __forceinline__ float sigmoid_s(float zs) {           // zs = LOG2E*z
    return fast_rcp(1.0f + exp2_f(-zs));
}
__device__ __forceinline__ float tanh_gs(float zs) {             // LOG2E*tanh(z)
    float t = fast_rcp(exp2_f(zs + zs) + 1.0f);
    return fmaf(-2.0f * LOG2E, t, LOG2E);
}
__device__ __forceinline__ float tanh_cs(float cs) {             // tanh(c), cs=LOG2E*c
    float t = fast_rcp(exp2_f(cs + cs) + 1.0f);
    return fmaf(-2.0f, t, 1.0f);
}
// lane i <- lane i-8 within each row of 16
__device__ __forceinline__ float dpp_shr8(float v) {
    int r = __builtin_amdgcn_update_dpp(0, __builtin_bit_cast(int, v),
                                        0x118, 0xF, 0xF, true);
    return __builtin_bit_cast(float, r);
}
// lane i <- lane i-4 within each row of 16
__device__ __forceinline__ float dpp_shr4(float v) {
    int r = __builtin_amdgcn_update_dpp(0, __builtin_bit_cast(int, v),
                                        0x114, 0xF, 0xF, true);
    return __builtin_bit_cast(float, r);
}

#define MFMA(A, B, C) __builtin_amdgcn_mfma_f32_16x16x32_bf16((A), (B), (C), 0, 0, 0)

__global__ __launch_bounds__(NTHREADS, 4)
void lstm_mfma_kernel(const float* __restrict__ x,
                      const float* __restrict__ W_ih,
                      const float* __restrict__ W_hh,
                      const float* __restrict__ b_ih,
                      const float* __restrict__ b_hh,
                      const float* __restrict__ W_out,
                      const float* __restrict__ b_out,
                      float* __restrict__ out)
{
    const int tid  = threadIdx.x;
    const int wv   = tid >> 6;        // wave 0..3 = unit-group (16wv..16wv+15)
    const int lane = tid & 63;
    const int q    = lane >> 4;       // quad
    const int cm   = lane & 15;
    const int b0   = blockIdx.x * MB;

    // h state, single rne-bf16, B-frag dword order, double-buffered.
    // element h[u][b]: dword 64*(u>>3) + 4*b + ((u&7)>>1), halfword u&1.
    // batch cols b=4..15 stay zero forever.
    __shared__ __align__(16) unsigned hbuf[2][512];

    // ---- resident A-frags (weights, pre-scaled by LOG2E), all single rne-bf16
    bf16x8 Whh[4][2], Wih[4];
    f32x4  bias_c[4];
    #pragma unroll
    for (int g = 0; g < 4; ++g) {
        const int gn = g * H_DIM + wv * 16 + cm;   // global gate row
        #pragma unroll
        for (int kt = 0; kt < 2; ++kt) {
            const float* wr = W_hh + gn * H_DIM + kt * 32 + q * 8;
            float wt[8];
            float4 wa = *(const float4*)wr;
            float4 wb = *(const float4*)(wr + 4);
            wt[0]=wa.x*LOG2E; wt[1]=wa.y*LOG2E; wt[2]=wa.z*LOG2E; wt[3]=wa.w*LOG2E;
            wt[4]=wb.x*LOG2E; wt[5]=wb.y*LOG2E; wt[6]=wb.z*LOG2E; wt[7]=wb.w*LOG2E;
            Whh[g][kt] = pack_frag(wt);
        }
        {
            const float* ir = W_ih + gn * I_DIM + q * 8;
            float wt[8];
            float4 ia = *(const float4*)ir;
            wt[0]=ia.x*LOG2E; wt[1]=ia.y*LOG2E; wt[2]=ia.z*LOG2E; wt[3]=ia.w*LOG2E;
            if (q < 3) {
                float4 ib = *(const float4*)(ir + 4);
                wt[4]=ib.x*LOG2E; wt[5]=ib.y*LOG2E; wt[6]=ib.z*LOG2E; wt[7]=ib.w*LOG2E;
            } else { wt[4]=0.f; wt[5]=0.f; wt[6]=0.f; wt[7]=0.f; }
            Wih[g] = pack_frag(wt);
        }
        #pragma unroll
        for (int r = 0; r < 4; ++r) {
            const int row = g * H_DIM + wv * 16 + 4 * q + r;
            bias_c[g][r] = (b_ih[row] + b_hh[row]) * LOG2E;
        }
    }

    // zero both h buffers
    for (int i = tid; i < 1024; i += NTHREADS)
        ((unsigned*)hbuf)[i] = 0u;

    // ---- per-lane x stream: lane (q,cm) supplies x[b0+(cm&3)][t][8q..8q+7]
    // (lanes cm>=4 duplicate batch cm&3 — L1 hit; their C cols are never read)
    const float* xp = x + ((size_t)(b0 + (cm & 3)) * T_DIM) * I_DIM + q * 8;
    auto load_pack = [&](const float* p) -> bf16x8 {
        float4 xa = *(const float4*)p;
        float4 xb;
        if (q < 3) xb = *(const float4*)(p + 4);
        else       xb = float4{0.f, 0.f, 0.f, 0.f};
        float xt[8];
        xt[0]=xa.x; xt[1]=xa.y; xt[2]=xa.z; xt[3]=xa.w;
        xt[4]=xb.x; xt[5]=xb.y; xt[6]=xb.z; xt[7]=xb.w;
        return pack_frag(xt);
    };
    bf16x8 Xcur = load_pack(xp);

    float c_st = 0.0f;   // scaled cell state (LOG2E*c), 1 cell/thread
    // cell ownership: unit u = 16wv + 4q + (cm>>2), batch b = cm&3
    const int u_own = 16 * wv + 4 * q + (cm >> 2);
    const int b_own = cm & 3;
    const int hhalf = (64 * (u_own >> 3) + 4 * b_own + ((u_own & 7) >> 1)) * 2
                    + (u_own & 1);   // halfword index into hbuf[wb]

    __syncthreads();   // zeros visible

    for (int t = 0; t < T_DIM; ++t) {
        const int rb = t & 1, wb = rb ^ 1;

        // issue x(t+1) loads first (latency hidden under the whole step)
        const float* pn = (t < T_DIM - 1) ? xp + I_DIM : xp;
        float4 xa_n = *(const float4*)pn;
        float4 xb_n;
        if (q < 3) xb_n = *(const float4*)(pn + 4);
        else       xb_n = float4{0.f, 0.f, 0.f, 0.f};
        xp = pn;

        // h(t) B-frags (lane-consecutive b128, conflict-free)
        bf16x8 H0 = __builtin_bit_cast(bf16x8, *(u32x4*)&hbuf[rb][lane * 4]);
        bf16x8 H1 = __builtin_bit_cast(bf16x8, *(u32x4*)&hbuf[rb][256 + lane * 4]);

        // 3-deep MFMA chain per gate: bias -> +Wih*x -> +Whh*h
        f32x4 acc[4];
        #pragma unroll
        for (int g = 0; g < 4; ++g) {
            f32x4 a = MFMA(Wih[g], Xcur, bias_c[g]);   // issues before H arrives
            a = MFMA(Whh[g][0], H0, a);
            a = MFMA(Whh[g][1], H1, a);
            acc[g] = a;
        }

        // 2-level redistribute: lane (q,cm) <- row (cm>>2), col (cm&3)
        float gv[4];
        #pragma unroll
        for (int g = 0; g < 4; ++g) {
            float a2 = dpp_shr8(acc[g][2]);
            float a3 = dpp_shr8(acc[g][3]);
            float v0 = (cm & 8) ? a2 : acc[g][0];
            float v1 = (cm & 8) ? a3 : acc[g][1];
            float v1s = dpp_shr4(v1);
            gv[g] = (cm & 4) ? v1s : v0;
        }

        // update 1 cell (preacts LOG2E-scaled)
        {
            float ig = sigmoid_s(gv[0]);
            float fg = sigmoid_s(gv[1]);
            float gs = tanh_gs (gv[2]);
            float og = sigmoid_s(gv[3]);
            float cc = fmaf(fg, c_st, ig * gs);
            c_st = cc;
            float hh = og * tanh_cs(cc);
            ((unsigned short*)&hbuf[wb][0])[hhalf] = (unsigned short)f2bf_rne(hh);
        }

        // pack x(t+1) frag for next step (overlaps nothing critical)
        {
            float xt[8];
            xt[0]=xa_n.x; xt[1]=xa_n.y; xt[2]=xa_n.z; xt[3]=xa_n.w;
            xt[4]=xb_n.x; xt[5]=xb_n.y; xt[6]=xb_n.z; xt[7]=xb_n.w;
            Xcur = pack_frag(xt);
        }

        __syncthreads();   // h(t+1) visible
    }

    // ---- output head: final h(T) is in hbuf[0] (T even)
    if (tid < MB * OUT_DIM) {
        const int bb = tid / OUT_DIM;
        const int o  = tid % OUT_DIM;
        float s = b_out[o];
        const float* wo = W_out + o * H_DIM;
        #pragma unroll
        for (int u = 0; u < H_DIM; ++u) {
            const int dw = 64 * (u >> 3) + 4 * bb + ((u & 7) >> 1);
            const int sh = (u & 1) * 16;
            float h = bfbits2f((hbuf[0][dw] >> sh) & 0xFFFFu);
            s += h * wo[u];
        }
        out[(size_t)(b0 + bb) * OUT_DIM + o] = s;
    }
}

extern "C" void kernel_launch(void* const* d_in, const int* in_sizes, int n_in,
                              void* d_out, int out_size, void* d_ws, size_t ws_size,
                              hipStream_t stream) {
    const float* x     = (const float*)d_in[0];
    const float* W_ih  = (const float*)d_in[1];
    const float* W_hh  = (const float*)d_in[2];
    const float* b_ih  = (const float*)d_in[3];
    const float* b_hh  = (const float*)d_in[4];
    const float* W_out = (const float*)d_in[5];
    const float* b_out = (const float*)d_in[6];
    float* out = (float*)d_out;

    dim3 grid(B_DIM / MB);    // 1024 blocks -> 4 per CU (4 independent streams)
    dim3 block(NTHREADS);     // 4 waves
    lstm_mfma_kernel<<<grid, block, 0, stream>>>(
        x, W_ih, W_hh, b_ih, b_hh, W_out, b_out, out);
}